// Round 7
// baseline (5560.036 us; speedup 1.0000x reference)
//
#include <hip/hip_runtime.h>
#include <cstdint>
#include <cstddef>

typedef _Float16 half8  __attribute__((ext_vector_type(8)));
typedef float    floatx4 __attribute__((ext_vector_type(4)));
typedef unsigned int uintx4 __attribute__((ext_vector_type(4)));

#define T_STEPS 1500
#define BATCH   16
#define FDIM    440
#define FPAD    448
#define HDIM    512
#define MROWS   (T_STEPS*BATCH)   /* 24000 */
#define NGATES  1024
#define SNAPE   8192              /* f16 elems per state snapshot (16x512) */
#define SNAPB   (SNAPE*2)         /* 16 KB */
#define POLL_BUDGET (1 << 14)

// ---------------- small utility kernels ----------------

__global__ __launch_bounds__(256) void cvt_pad(const float* __restrict__ src,
                                               _Float16* __restrict__ dst,
                                               int src_cols, int dst_cols) {
    int row = blockIdx.x;
    for (int k = threadIdx.x; k < dst_cols; k += 256) {
        float v = (k < src_cols) ? src[(size_t)row * src_cols + k] : 0.f;
        dst[(size_t)row * dst_cols + k] = (_Float16)v;
    }
}

__global__ __launch_bounds__(256) void cat2(const float* __restrict__ a,
                                            const float* __restrict__ b,
                                            float* __restrict__ dst) {
    int i = blockIdx.x * 256 + threadIdx.x;
    if (i < 1024) dst[i] = (i < 512) ? a[i] : b[i - 512];
}

// ---------------- GEMM: C[M,1024] = A[M,Kp] * B[1024,Kp]^T + bias (layer 0 gates) ----

__global__ __launch_bounds__(256) void gemm_tn(const _Float16* __restrict__ A,
                                               const _Float16* __restrict__ B,
                                               const float* __restrict__ bias,
                                               float* __restrict__ C32,
                                               _Float16* __restrict__ C16,
                                               int M, int Kp, int use_f32) {
    __shared__ _Float16 As[128 * 40];
    __shared__ _Float16 Bs[128 * 40];

    const int tid = threadIdx.x;
    const int wv = tid >> 6, l = tid & 63, q = l >> 4, c = l & 15;
    const int wr = wv >> 1, wc = wv & 1;
    const int m0 = blockIdx.y * 128, n0 = blockIdx.x * 128;

    floatx4 acc[4][4] = {};

    for (int kt = 0; kt < Kp; kt += 32) {
#pragma unroll
        for (int i = 0; i < 2; ++i) {
            int s = tid + i * 256;
            int row = s >> 2, qq = s & 3;
            uint4 va = {0u, 0u, 0u, 0u};
            int gm = m0 + row;
            if (gm < M) va = *(const uint4*)(A + (size_t)gm * Kp + kt + qq * 8);
            *(uint4*)(As + row * 40 + qq * 8) = va;
            uint4 vb = *(const uint4*)(B + (size_t)(n0 + row) * Kp + kt + qq * 8);
            *(uint4*)(Bs + row * 40 + qq * 8) = vb;
        }
        __syncthreads();

        half8 af[4], bf[4];
#pragma unroll
        for (int mi = 0; mi < 4; ++mi)
            af[mi] = *(const half8*)(As + (wr * 64 + mi * 16 + c) * 40 + q * 8);
#pragma unroll
        for (int ni = 0; ni < 4; ++ni)
            bf[ni] = *(const half8*)(Bs + (wc * 64 + ni * 16 + c) * 40 + q * 8);
#pragma unroll
        for (int mi = 0; mi < 4; ++mi)
#pragma unroll
            for (int ni = 0; ni < 4; ++ni)
                acc[mi][ni] = __builtin_amdgcn_mfma_f32_16x16x32_f16(af[mi], bf[ni], acc[mi][ni], 0, 0, 0);
        __syncthreads();
    }

#pragma unroll
    for (int ni = 0; ni < 4; ++ni) {
        int n = n0 + wc * 64 + ni * 16 + c;
        float bv = bias[n];
#pragma unroll
        for (int mi = 0; mi < 4; ++mi) {
#pragma unroll
            for (int r = 0; r < 4; ++r) {
                int gm = m0 + wr * 64 + mi * 16 + q * 4 + r;
                if (gm < M) {
                    float v = acc[mi][ni][r] + bv;
                    if (use_f32) C32[(size_t)gm * NGATES + n] = v;
                    else         C16[(size_t)gm * NGATES + n] = (_Float16)v;
                }
            }
        }
    }
}

// ---------------- MALL-coherent exchange primitives (sc0 sc1 = agent scope) ----------------

__device__ __forceinline__ void st32cc(uint32_t* p, uint32_t v) {
    asm volatile("global_store_dword %0, %1, off sc0 sc1" :: "v"(p), "v"(v) : "memory");
}
__device__ __forceinline__ void st16cc(void* p, unsigned v) {
    asm volatile("global_store_short %0, %1, off sc0 sc1" :: "v"(p), "v"(v) : "memory");
}
__device__ __forceinline__ void ld32B(const char* p, uintx4& A, uintx4& B) {
    asm volatile("global_load_dwordx4 %0, %2, off sc0 sc1\n\t"
                 "global_load_dwordx4 %1, %2, off offset:16 sc0 sc1\n\t"
                 "s_waitcnt vmcnt(0)"
                 : "=&v"(A), "=&v"(B) : "v"(p) : "memory");
}
// exC 32B + the two G1 gate dwords (h-part at +0, z-part at +1024B) in one round trip
__device__ __forceinline__ void ldmix(const char* pc, const char* pg,
                                      uintx4& A, uintx4& B, unsigned& g0, unsigned& g1) {
    asm volatile("global_load_dwordx4 %0, %4, off sc0 sc1\n\t"
                 "global_load_dwordx4 %1, %4, off offset:16 sc0 sc1\n\t"
                 "global_load_dword %2, %5, off sc0 sc1\n\t"
                 "global_load_dword %3, %5, off offset:1024 sc0 sc1\n\t"
                 "s_waitcnt vmcnt(0)"
                 : "=&v"(A), "=&v"(B), "=&v"(g0), "=&v"(g1) : "v"(pc), "v"(pg) : "memory");
}
// 8 flags in one round trip
__device__ __forceinline__ void ld8f(const unsigned* p, uintx4& A, uintx4& B) {
    asm volatile("global_load_dwordx4 %0, %2, off sc0 sc1\n\t"
                 "global_load_dwordx4 %1, %2, off offset:16 sc0 sc1\n\t"
                 "s_waitcnt vmcnt(0)"
                 : "=&v"(A), "=&v"(B) : "v"(p) : "memory");
}
// 8 flags + one flagP dword in one round trip
__device__ __forceinline__ void ld8f1(const unsigned* p8, const unsigned* p1,
                                      uintx4& A, uintx4& B, unsigned& C) {
    asm volatile("global_load_dwordx4 %0, %3, off sc0 sc1\n\t"
                 "global_load_dwordx4 %1, %3, off offset:16 sc0 sc1\n\t"
                 "global_load_dword %2, %4, off sc0 sc1\n\t"
                 "s_waitcnt vmcnt(0)"
                 : "=&v"(A), "=&v"(B), "=&v"(C) : "v"(p8), "v"(p1) : "memory");
}
// scatter thread j's 32B (feats [(j&31)*16, +16) of batch j>>5) into frag-major LDS
__device__ __forceinline__ void scat(char* lds, int j, uintx4 A, uintx4 B) {
    const int b = j >> 5, g = j & 31;
    const int ks = g >> 1, qp = (g & 1) * 2;
    *(uintx4*)(lds + ks * 1040 + (qp * 16 + b) * 16)       = A;
    *(uintx4*)(lds + ks * 1040 + ((qp + 1) * 16 + b) * 16) = B;
}

// ---------------- fused 2-layer persistent scan + projection offload ----------------
// 80 WGs x 512 thr.
//   WGs 0-7  : layer-0 scan (64 feats each), weights in registers.
//   WGs 8-15 : layer-1 scan (U-recurrence ONLY; the W1*h0 part is consumed
//              precomputed from G1 -- off the serial chain).
//   WGs 16-79: projection workers. Task t: wait flagsA >= t+1, read H1T[t],
//              compute G1[t] = [W1h*h0_t | W1z*h0_t] (weights streamed from L2),
//              store f16 + drain + flagP[t]=1.  Projections are throughput-
//              parallel across t, so they add a constant lag, not a rate limit.
// Release protocol everywhere: store data -> s_waitcnt(0) -> barrier -> flag store
// (proven in R0/R2/R5; counted-vmcnt releases raced in R1 -- do not reintroduce).
// accS padded [16]->[17] (R5: broke the 32-way epilogue bank conflict).
//
// R7 fix (the R6 bug): the early-issued gate prefetch gload(t+2, s) writes the
// SAME double-buffer slot (s = t&1 = (t+2)&1) the current step consumes. The
// current gates must be copied to locals BEFORE the prefetch is issued.

__global__ __launch_bounds__(512, 1) void ligru_fused(
        const float* __restrict__ gates32, const _Float16* __restrict__ gates16,
        const _Float16* __restrict__ U0z, const _Float16* __restrict__ U0h,
        const _Float16* __restrict__ U1z, const _Float16* __restrict__ U1h,
        const _Float16* __restrict__ W1z, const _Float16* __restrict__ W1h,
        unsigned int* __restrict__ flg,     // [0..7]=layer0 steps done, [8..15]=layer1
        unsigned int* __restrict__ flagP,   // [T_STEPS] projection-done flags
        _Float16* __restrict__ exA,         // [2][SNAPE] layer-0 h ring
        _Float16* __restrict__ exC,         // [2][SNAPE] layer-1 h ring
        _Float16* __restrict__ H1T,         // [T_STEPS][SNAPE] layer-0 outputs
        _Float16* __restrict__ G1,          // [T_STEPS][16][1024] W1-projected gates
        const float* __restrict__ bh1, const float* __restrict__ bz1,
        float* __restrict__ out, int use_gf32) {

    __shared__ char ldsX[16 * 1040];
    __shared__ float accS[2][4][16][17];

    const int tid = threadIdx.x;
    const int l = tid & 63, wv = tid >> 6, q = l >> 4, c = l & 15;
    const int gate = wv >> 2, ti = wv & 3;           // 8 waves = 2 gates x 4 tiles
    const int wg = blockIdx.x & 7;
    const int fbase = wg * 64;

    const int eb  = tid >> 5;                        // batch
    const int fpl = tid & 31;
    const int f0  = 2 * fpl;
    const int gf  = fbase + f0;                      // global feature (even)
    const int eti = f0 >> 4, efi = f0 & 15;

    int dead = 0;                                    // tid0 only: poll fail-safe

    if (blockIdx.x < 8) {
        // ---- layer 0 ----
        const _Float16* U = (gate == 0) ? U0z : U0h;
        const int urow = fbase + ti * 16 + c;
        half8 u[16];
#pragma unroll
        for (int ks = 0; ks < 16; ++ks)
            u[ks] = *(const half8*)(U + (size_t)urow * HDIM + ks * 32 + q * 8);
#pragma unroll
        for (int ks = 0; ks < 16; ++ks)
            asm volatile("" : "+v"(u[ks]));

        float h0 = 0.f, h1 = 0.f;
        float gw0[2], gw1[2], gz0[2], gz1[2];        // 2-step gate prefetch
        auto gload = [&](int t, int s) {
            const int row = t * BATCH + eb;
            if (use_gf32) {
                float2 a2 = *(const float2*)(gates32 + (size_t)row * NGATES + gf);
                float2 b2 = *(const float2*)(gates32 + (size_t)row * NGATES + 512 + gf);
                gw0[s] = a2.x; gw1[s] = a2.y; gz0[s] = b2.x; gz1[s] = b2.y;
            } else {
                union { uint32_t u; _Float16 h[2]; } ua, ub;
                ua.u = *(const uint32_t*)(gates16 + (size_t)row * NGATES + gf);
                ub.u = *(const uint32_t*)(gates16 + (size_t)row * NGATES + 512 + gf);
                gw0[s] = (float)ua.h[0]; gw1[s] = (float)ua.h[1];
                gz0[s] = (float)ub.h[0]; gz1[s] = (float)ub.h[1];
            }
        };
        gload(0, 0);
        gload(1, 1);

        for (int t = 0; t < T_STEPS; ++t) {
            // gate: exA[t&1] complete == all layer-0 flags >= t
            if (tid == 0 && !dead) {
                int bud = POLL_BUDGET;
                for (;;) {
                    unsigned ok = 1u;
#pragma unroll
                    for (int i = 0; i < 8; ++i) {
                        unsigned v = __hip_atomic_load(&flg[i], __ATOMIC_RELAXED, __HIP_MEMORY_SCOPE_AGENT);
                        ok &= (v >= (unsigned)t) ? 1u : 0u;
                    }
                    if (ok) break;
                    __builtin_amdgcn_s_sleep(1);
                    if (--bud < 0) { dead = 1; break; }
                }
            }
            __syncthreads();

            // consume slot s into locals BEFORE the t+2 prefetch overwrites it
            const int s = t & 1;
            const float cw0 = gw0[s], cw1 = gw1[s], cz0 = gz0[s], cz1 = gz1[s];

            uintx4 A, B;
            ld32B((const char*)(exA + (size_t)(t & 1) * SNAPE) + tid * 32, A, B);
            // issue the t+2 gate prefetch NOW: it completes during the MFMA phase,
            // so the end-of-step drain waits only on the two exchange stores
            if (t + 2 < T_STEPS) gload(t + 2, s);
            scat(ldsX, tid, A, B);
            __syncthreads();

            floatx4 ac0 = {0.f, 0.f, 0.f, 0.f}, ac1 = {0.f, 0.f, 0.f, 0.f};
#pragma unroll
            for (int ks = 0; ks < 16; ks += 2) {
                half8 a0 = *(const half8*)(ldsX + ks * 1040 + l * 16);
                half8 a1 = *(const half8*)(ldsX + (ks + 1) * 1040 + l * 16);
                ac0 = __builtin_amdgcn_mfma_f32_16x16x32_f16(a0, u[ks],     ac0, 0, 0, 0);
                ac1 = __builtin_amdgcn_mfma_f32_16x16x32_f16(a1, u[ks + 1], ac1, 0, 0, 0);
            }
            floatx4 acc = ac0 + ac1;
#pragma unroll
            for (int r = 0; r < 4; ++r) accS[gate][ti][c][q * 4 + r] = acc[r];
            __syncthreads();

            float Sz0 = accS[0][eti][efi][eb],     Sh0 = accS[1][eti][efi][eb];
            float Sz1 = accS[0][eti][efi + 1][eb], Sh1 = accS[1][eti][efi + 1][eb];

            float z0 = 1.f / (1.f + __expf(-(cz0 + Sz0)));
            float z1 = 1.f / (1.f + __expf(-(cz1 + Sz1)));
            float hc0 = fmaxf(0.f, cw0 + Sh0);
            float hc1 = fmaxf(0.f, cw1 + Sh1);
            h0 = z0 * h0 + (1.f - z0) * hc0;
            h1 = z1 * h1 + (1.f - z1) * hc1;

            union { _Float16 h[2]; uint32_t u; } pk;
            pk.h[0] = (_Float16)h0; pk.h[1] = (_Float16)h1;
            st32cc((uint32_t*)(exA + (size_t)((t + 1) & 1) * SNAPE + eb * HDIM + gf), pk.u);
            st32cc((uint32_t*)(H1T + (size_t)t * SNAPE + eb * HDIM + gf), pk.u);

            __builtin_amdgcn_s_waitcnt(0);           // data acked at MALL
            __syncthreads();
            if (tid == 0) st32cc(&flg[wg], (unsigned)(t + 1));   // release
        }
    } else if (blockIdx.x < 16) {
        // ---- layer 1 (U-recurrence only; W1*h0 consumed precomputed from G1) ----
        const _Float16* Um = (gate == 0) ? U1z : U1h;
        const int urow = fbase + ti * 16 + c;
        half8 u[16];
#pragma unroll
        for (int ks = 0; ks < 16; ++ks)
            u[ks] = *(const half8*)(Um + (size_t)urow * HDIM + ks * 32 + q * 8);
#pragma unroll
        for (int ks = 0; ks < 16; ++ks)
            asm volatile("" : "+v"(u[ks]));

        const float bzv0 = bz1[gf], bzv1 = bz1[gf + 1];
        const float bhv0 = bh1[gf], bhv1 = bh1[gf + 1];
        float h0 = 0.f, h1 = 0.f;

        for (int t = 0; t < T_STEPS; ++t) {
            // gate: G1[t] ready (flagP[t]!=0, implies flagsA >= t+1) and exC[t&1] (flagsC >= t)
            if (tid == 0 && !dead) {
                int bud = POLL_BUDGET;
                const unsigned tc = (unsigned)t;
                for (;;) {
                    uintx4 fa, fb; unsigned fp;
                    ld8f1(flg + 8, flagP + t, fa, fb, fp);
                    unsigned ok = (fp != 0u) ? 1u : 0u;
#pragma unroll
                    for (int i = 0; i < 4; ++i) {
                        ok &= (fa[i] >= tc) ? 1u : 0u;
                        ok &= (fb[i] >= tc) ? 1u : 0u;
                    }
                    if (ok) break;
                    __builtin_amdgcn_s_sleep(1);
                    if (--bud < 0) { dead = 1; break; }
                }
            }
            __syncthreads();

            uintx4 A, B; unsigned gh, gz;
            ldmix((const char*)(exC + (size_t)(t & 1) * SNAPE) + tid * 32,
                  (const char*)(G1 + ((size_t)t * BATCH + eb) * NGATES + gf), A, B, gh, gz);
            scat(ldsX, tid, A, B);
            __syncthreads();

            floatx4 ac0 = {0.f, 0.f, 0.f, 0.f}, ac1 = {0.f, 0.f, 0.f, 0.f};
#pragma unroll
            for (int ks = 0; ks < 16; ks += 2) {
                half8 a0 = *(const half8*)(ldsX + ks * 1040 + l * 16);
                half8 a1 = *(const half8*)(ldsX + (ks + 1) * 1040 + l * 16);
                ac0 = __builtin_amdgcn_mfma_f32_16x16x32_f16(a0, u[ks],     ac0, 0, 0, 0);
                ac1 = __builtin_amdgcn_mfma_f32_16x16x32_f16(a1, u[ks + 1], ac1, 0, 0, 0);
            }
            floatx4 acc = ac0 + ac1;
#pragma unroll
            for (int r = 0; r < 4; ++r) accS[gate][ti][c][q * 4 + r] = acc[r];
            __syncthreads();

            float Sz0 = accS[0][eti][efi][eb],     Sh0 = accS[1][eti][efi][eb];
            float Sz1 = accS[0][eti][efi + 1][eb], Sh1 = accS[1][eti][efi + 1][eb];

            union { uint32_t u; _Float16 h[2]; } uh, uz;
            uh.u = gh; uz.u = gz;

            float z0 = 1.f / (1.f + __expf(-(bzv0 + (float)uz.h[0] + Sz0)));
            float z1 = 1.f / (1.f + __expf(-(bzv1 + (float)uz.h[1] + Sz1)));
            float hc0 = fmaxf(0.f, bhv0 + (float)uh.h[0] + Sh0);
            float hc1 = fmaxf(0.f, bhv1 + (float)uh.h[1] + Sh1);
            h0 = z0 * h0 + (1.f - z0) * hc0;
            h1 = z1 * h1 + (1.f - z1) * hc1;

            union { _Float16 h[2]; uint32_t u; } pk;
            pk.h[0] = (_Float16)h0; pk.h[1] = (_Float16)h1;
            st32cc((uint32_t*)(exC + (size_t)((t + 1) & 1) * SNAPE + eb * HDIM + gf), pk.u);

            float2 o; o.x = h0; o.y = h1;
            *(float2*)(out + (size_t)(t * BATCH + eb) * HDIM + gf) = o;  // final output (plain)

            __builtin_amdgcn_s_waitcnt(0);
            __syncthreads();
            if (tid == 0) st32cc(&flg[8 + wg], (unsigned)(t + 1));
        }
    } else {
        // ---- projection workers: G1[t] = [W1h*h0_t | W1z*h0_t] ----
        const int p = blockIdx.x - 16;               // 0..63
        const int cb = wv * 128;                     // this wave's 128-col slab
        const _Float16* Wp = (cb < 512) ? (W1h + (size_t)cb * HDIM)
                                        : (W1z + (size_t)(cb - 512) * HDIM);

        for (int t = p; t < T_STEPS; t += 64) {
            if (tid == 0 && !dead) {
                int bud = POLL_BUDGET;
                const unsigned ta = (unsigned)(t + 1);
                for (;;) {
                    uintx4 fa, fb;
                    ld8f(flg, fa, fb);
                    unsigned ok = 1u;
#pragma unroll
                    for (int i = 0; i < 4; ++i) {
                        ok &= (fa[i] >= ta) ? 1u : 0u;
                        ok &= (fb[i] >= ta) ? 1u : 0u;
                    }
                    if (ok) break;
                    __builtin_amdgcn_s_sleep(1);
                    if (--bud < 0) { dead = 1; break; }
                }
            }
            __syncthreads();

            uintx4 A, B;
            ld32B((const char*)(H1T + (size_t)t * SNAPE) + tid * 32, A, B);
            scat(ldsX, tid, A, B);
            __syncthreads();

            floatx4 acc[8] = {};
            for (int ks = 0; ks < 16; ++ks) {
                half8 a = *(const half8*)(ldsX + ks * 1040 + l * 16);
#pragma unroll
                for (int ct = 0; ct < 8; ++ct) {
                    half8 wf = *(const half8*)(Wp + (size_t)(ct * 16 + c) * HDIM + ks * 32 + q * 8);
                    acc[ct] = __builtin_amdgcn_mfma_f32_16x16x32_f16(a, wf, acc[ct], 0, 0, 0);
                }
            }

            _Float16* gdst = G1 + (size_t)t * BATCH * NGATES;
#pragma unroll
            for (int ct = 0; ct < 8; ++ct) {
                const int col = cb + ct * 16 + c;
#pragma unroll
                for (int r = 0; r < 4; ++r) {
                    union { _Float16 h; unsigned short s; } cv;
                    cv.h = (_Float16)acc[ct][r];
                    st16cc(gdst + (size_t)(q * 4 + r) * NGATES + col, (unsigned)cv.s);
                }
            }

            __builtin_amdgcn_s_waitcnt(0);           // G1 acked at MALL
            __syncthreads();                          // also guards ldsX reuse next task
            if (tid == 0) st32cc(&flagP[t], 1u);
        }
    }
}

// ---------------- host ----------------

extern "C" void kernel_launch(void* const* d_in, const int* in_sizes, int n_in,
                              void* d_out, int out_size, void* d_ws, size_t ws_size,
                              hipStream_t stream) {
    const float* x   = (const float*)d_in[0];
    const float* Wh0 = (const float*)d_in[1];
    const float* bh0 = (const float*)d_in[2];
    const float* Wz0 = (const float*)d_in[3];
    const float* bz0 = (const float*)d_in[4];
    const float* Uh0 = (const float*)d_in[5];
    const float* Uz0 = (const float*)d_in[6];
    const float* Wh1 = (const float*)d_in[7];
    const float* bh1 = (const float*)d_in[8];
    const float* Wz1 = (const float*)d_in[9];
    const float* bz1 = (const float*)d_in[10];
    const float* Uh1 = (const float*)d_in[11];
    const float* Uz1 = (const float*)d_in[12];
    float* out = (float*)d_out;

    uint8_t* ws = (uint8_t*)d_ws;
    size_t off = 0;
    auto alloc = [&](size_t b) { size_t o = off; off += (b + 255) & ~(size_t)255; return o; };

    const size_t H1TB = (size_t)T_STEPS * SNAPB;         // 24 MB layer-0 outputs
    const size_t G1B  = (size_t)T_STEPS * BATCH * NGATES * 2;  // 48 MB projected gates
    size_t o_flg  = alloc(256);                          // flg[16]
    size_t o_fp   = alloc(T_STEPS * 4);                  // flagP[1500] (6 KB)
    size_t o_exA  = alloc(2 * SNAPB);
    size_t o_exC  = alloc(2 * SNAPB);
    size_t o_h1t  = alloc(H1TB);                         // flag-gated; no init needed
    size_t o_g1   = alloc(G1B);                          // flag-gated; no init needed
    size_t o_U0z  = alloc((size_t)HDIM * HDIM * 2);
    size_t o_U0h  = alloc((size_t)HDIM * HDIM * 2);
    size_t o_U1z  = alloc((size_t)HDIM * HDIM * 2);
    size_t o_U1h  = alloc((size_t)HDIM * HDIM * 2);
    size_t o_W1z  = alloc((size_t)HDIM * HDIM * 2);
    size_t o_W1h  = alloc((size_t)HDIM * HDIM * 2);
    size_t o_Wc0  = alloc((size_t)NGATES * FPAD * 2);
    size_t o_b0   = alloc(1024 * 4);
    size_t o_xb   = alloc((size_t)MROWS * FPAD * 2);
    size_t o_g    = off;
    size_t need32 = off + (size_t)MROWS * NGATES * 4;
    int use_gf32 = (ws_size >= need32) ? 1 : 0;

    unsigned int* FLG = (unsigned int*)(ws + o_flg);
    unsigned int* FLP = (unsigned int*)(ws + o_fp);
    _Float16* EXA = (_Float16*)(ws + o_exA);
    _Float16* EXC = (_Float16*)(ws + o_exC);
    _Float16* H1T = (_Float16*)(ws + o_h1t);
    _Float16* G1  = (_Float16*)(ws + o_g1);
    _Float16* U0Z = (_Float16*)(ws + o_U0z);
    _Float16* U0H = (_Float16*)(ws + o_U0h);
    _Float16* U1Z = (_Float16*)(ws + o_U1z);
    _Float16* U1H = (_Float16*)(ws + o_U1h);
    _Float16* W1Z = (_Float16*)(ws + o_W1z);
    _Float16* W1H = (_Float16*)(ws + o_W1h);
    _Float16* WC0 = (_Float16*)(ws + o_Wc0);
    float*    B0  = (float*)(ws + o_b0);
    _Float16* XB  = (_Float16*)(ws + o_xb);
    float*    G32 = (float*)(ws + o_g);
    _Float16* G16 = (_Float16*)(ws + o_g);

    // zero flags + flagP + both h rings (contiguous, 256-aligned sizes)
    hipMemsetAsync(ws + o_flg, 0, (o_exC - o_flg) + 2 * SNAPB, stream);

    // fp32 -> fp16 conversions (with K padding for layer-0 GEMM)
    cvt_pad<<<MROWS, 256, 0, stream>>>(x, XB, FDIM, FPAD);
    cvt_pad<<<512, 256, 0, stream>>>(Wh0, WC0,              FDIM, FPAD);
    cvt_pad<<<512, 256, 0, stream>>>(Wz0, WC0 + 512 * FPAD, FDIM, FPAD);
    cvt_pad<<<512, 256, 0, stream>>>(Uz0, U0Z, HDIM, HDIM);
    cvt_pad<<<512, 256, 0, stream>>>(Uh0, U0H, HDIM, HDIM);
    cvt_pad<<<512, 256, 0, stream>>>(Uz1, U1Z, HDIM, HDIM);
    cvt_pad<<<512, 256, 0, stream>>>(Uh1, U1H, HDIM, HDIM);
    cvt_pad<<<512, 256, 0, stream>>>(Wz1, W1Z, HDIM, HDIM);
    cvt_pad<<<512, 256, 0, stream>>>(Wh1, W1H, HDIM, HDIM);
    cat2<<<4, 256, 0, stream>>>(bh0, bz0, B0);

    // layer-0 gates GEMM (layer-1 projection handled by in-scan projection WGs)
    dim3 gg(NGATES / 128, (MROWS + 127) / 128);
    gemm_tn<<<gg, 256, 0, stream>>>(XB, WC0, B0, G32, G16, MROWS, FPAD, use_gf32);

    // fused 2-layer scan + 64 projection WGs, flag-gated MALL exchange
    ligru_fused<<<80, 512, 0, stream>>>(G32, G16, U0Z, U0H, U1Z, U1H, W1Z, W1H,
                                        FLG, FLP, EXA, EXC, H1T, G1, bh1, bz1, out, use_gf32);

    (void)in_sizes; (void)n_in; (void)out_size;
}

// Round 8
// 4975.655 us; speedup vs baseline: 1.1174x; 1.1174x over previous
//
#include <hip/hip_runtime.h>
#include <cstdint>
#include <cstddef>

typedef _Float16 half8  __attribute__((ext_vector_type(8)));
typedef float    floatx4 __attribute__((ext_vector_type(4)));
typedef unsigned int uintx4 __attribute__((ext_vector_type(4)));

#define T_STEPS 1500
#define BATCH   16
#define FDIM    440
#define FPAD    448
#define HDIM    512
#define MROWS   (T_STEPS*BATCH)   /* 24000 */
#define NGATES  1024
#define SNAPE   8192              /* f16 elems per state snapshot (16x512) */
#define SNAPB   (SNAPE*2)         /* 16 KB */
#define POLL_BUDGET (1 << 14)

// ---------------- small utility kernels ----------------

__global__ __launch_bounds__(256) void cvt_pad(const float* __restrict__ src,
                                               _Float16* __restrict__ dst,
                                               int src_cols, int dst_cols) {
    int row = blockIdx.x;
    for (int k = threadIdx.x; k < dst_cols; k += 256) {
        float v = (k < src_cols) ? src[(size_t)row * src_cols + k] : 0.f;
        dst[(size_t)row * dst_cols + k] = (_Float16)v;
    }
}

__global__ __launch_bounds__(256) void cat2(const float* __restrict__ a,
                                            const float* __restrict__ b,
                                            float* __restrict__ dst) {
    int i = blockIdx.x * 256 + threadIdx.x;
    if (i < 1024) dst[i] = (i < 512) ? a[i] : b[i - 512];
}

// ---------------- GEMM: C[M,1024] = A[M,Kp] * B[1024,Kp]^T + bias (layer 0 gates) ----

__global__ __launch_bounds__(256) void gemm_tn(const _Float16* __restrict__ A,
                                               const _Float16* __restrict__ B,
                                               const float* __restrict__ bias,
                                               float* __restrict__ C32,
                                               _Float16* __restrict__ C16,
                                               int M, int Kp, int use_f32) {
    __shared__ _Float16 As[128 * 40];
    __shared__ _Float16 Bs[128 * 40];

    const int tid = threadIdx.x;
    const int wv = tid >> 6, l = tid & 63, q = l >> 4, c = l & 15;
    const int wr = wv >> 1, wc = wv & 1;
    const int m0 = blockIdx.y * 128, n0 = blockIdx.x * 128;

    floatx4 acc[4][4] = {};

    for (int kt = 0; kt < Kp; kt += 32) {
#pragma unroll
        for (int i = 0; i < 2; ++i) {
            int s = tid + i * 256;
            int row = s >> 2, qq = s & 3;
            uint4 va = {0u, 0u, 0u, 0u};
            int gm = m0 + row;
            if (gm < M) va = *(const uint4*)(A + (size_t)gm * Kp + kt + qq * 8);
            *(uint4*)(As + row * 40 + qq * 8) = va;
            uint4 vb = *(const uint4*)(B + (size_t)(n0 + row) * Kp + kt + qq * 8);
            *(uint4*)(Bs + row * 40 + qq * 8) = vb;
        }
        __syncthreads();

        half8 af[4], bf[4];
#pragma unroll
        for (int mi = 0; mi < 4; ++mi)
            af[mi] = *(const half8*)(As + (wr * 64 + mi * 16 + c) * 40 + q * 8);
#pragma unroll
        for (int ni = 0; ni < 4; ++ni)
            bf[ni] = *(const half8*)(Bs + (wc * 64 + ni * 16 + c) * 40 + q * 8);
#pragma unroll
        for (int mi = 0; mi < 4; ++mi)
#pragma unroll
            for (int ni = 0; ni < 4; ++ni)
                acc[mi][ni] = __builtin_amdgcn_mfma_f32_16x16x32_f16(af[mi], bf[ni], acc[mi][ni], 0, 0, 0);
        __syncthreads();
    }

#pragma unroll
    for (int ni = 0; ni < 4; ++ni) {
        int n = n0 + wc * 64 + ni * 16 + c;
        float bv = bias[n];
#pragma unroll
        for (int mi = 0; mi < 4; ++mi) {
#pragma unroll
            for (int r = 0; r < 4; ++r) {
                int gm = m0 + wr * 64 + mi * 16 + q * 4 + r;
                if (gm < M) {
                    float v = acc[mi][ni][r] + bv;
                    if (use_f32) C32[(size_t)gm * NGATES + n] = v;
                    else         C16[(size_t)gm * NGATES + n] = (_Float16)v;
                }
            }
        }
    }
}

// ---------------- MALL-coherent exchange primitives (sc0 sc1 = agent scope) ----------------

__device__ __forceinline__ void st32cc(uint32_t* p, uint32_t v) {
    asm volatile("global_store_dword %0, %1, off sc0 sc1" :: "v"(p), "v"(v) : "memory");
}
__device__ __forceinline__ void ld32B(const char* p, uintx4& A, uintx4& B) {
    asm volatile("global_load_dwordx4 %0, %2, off sc0 sc1\n\t"
                 "global_load_dwordx4 %1, %2, off offset:16 sc0 sc1\n\t"
                 "s_waitcnt vmcnt(0)"
                 : "=&v"(A), "=&v"(B) : "v"(p) : "memory");
}
__device__ __forceinline__ void ld32Bx2(const char* p1, const char* p2,
                                        uintx4& A, uintx4& B, uintx4& C, uintx4& D) {
    asm volatile("global_load_dwordx4 %0, %4, off sc0 sc1\n\t"
                 "global_load_dwordx4 %1, %4, off offset:16 sc0 sc1\n\t"
                 "global_load_dwordx4 %2, %5, off sc0 sc1\n\t"
                 "global_load_dwordx4 %3, %5, off offset:16 sc0 sc1\n\t"
                 "s_waitcnt vmcnt(0)"
                 : "=&v"(A), "=&v"(B), "=&v"(C), "=&v"(D) : "v"(p1), "v"(p2) : "memory");
}
// 8 flags in one round trip
__device__ __forceinline__ void ld8f(const unsigned* p, uintx4& A, uintx4& B) {
    asm volatile("global_load_dwordx4 %0, %2, off sc0 sc1\n\t"
                 "global_load_dwordx4 %1, %2, off offset:16 sc0 sc1\n\t"
                 "s_waitcnt vmcnt(0)"
                 : "=&v"(A), "=&v"(B) : "v"(p) : "memory");
}
// 16 flags in one round trip
__device__ __forceinline__ void ld16f(const unsigned* p, uintx4& A, uintx4& B, uintx4& C, uintx4& D) {
    asm volatile("global_load_dwordx4 %0, %4, off sc0 sc1\n\t"
                 "global_load_dwordx4 %1, %4, off offset:16 sc0 sc1\n\t"
                 "global_load_dwordx4 %2, %4, off offset:32 sc0 sc1\n\t"
                 "global_load_dwordx4 %3, %4, off offset:48 sc0 sc1\n\t"
                 "s_waitcnt vmcnt(0)"
                 : "=&v"(A), "=&v"(B), "=&v"(C), "=&v"(D) : "v"(p), "v"(p) : "memory");
}
// scatter thread j's 32B (feats [(j&31)*16, +16) of batch j>>5) into frag-major LDS
__device__ __forceinline__ void scat(char* lds, int j, uintx4 A, uintx4 B) {
    const int b = j >> 5, g = j & 31;
    const int ks = g >> 1, qp = (g & 1) * 2;
    *(uintx4*)(lds + ks * 1040 + (qp * 16 + b) * 16)       = A;
    *(uintx4*)(lds + ks * 1040 + ((qp + 1) * 16 + b) * 16) = B;
}

// ---------------- fused 2-layer persistent scan, flag-gated MALL exchange ----------------
// 16 WGs x 512 thr. WGs 0-7: layer-0 (64 feats each); WGs 8-15: layer-1.
// R8 = R5 (best proven, 4818us) + three local changes:
//  (a) l0 gate prefetch issued right after the data read, current values copied to
//      locals first (R7-proven fix) -- takes the gate HBM/MALL loads OUT of the
//      end-of-step drain (RT3 waits only on the exchange store).
//  (b) exA ring removed: l0 writes ONLY the append-only H1TX[t+1] (row-major,
//      byte-identical addressing to exA; slot 0 zeroed = h(-1)); l0 peers read
//      H1TX[t], l1 reads H1TX[t+1]. One store in the drain instead of two; no WAR.
//      (NOT R3's frag-major rewrite -- layout unchanged from R5.)
//  (c) MFMA accumulator split 2 -> 4 chains (halves dependent-MFMA depth).
// Protocol unchanged: store -> s_waitcnt(0) -> barrier -> flag (R0/R2/R5-proven).
// accS padded [16]->[17] (R5: broke the 32-way epilogue bank conflict).

__global__ __launch_bounds__(512, 1) void ligru_fused(
        const float* __restrict__ gates32, const _Float16* __restrict__ gates16,
        const _Float16* __restrict__ U0z, const _Float16* __restrict__ U0h,
        const _Float16* __restrict__ U1z, const _Float16* __restrict__ U1h,
        const _Float16* __restrict__ W1z, const _Float16* __restrict__ W1h,
        unsigned int* __restrict__ flg,     // [0..7]=layer0 steps done, [8..15]=layer1
        _Float16* __restrict__ exC,         // [2][SNAPE] layer-1 h ring
        _Float16* __restrict__ H1TX,        // [T_STEPS+1][SNAPE]; slot 0 = zeroed h(-1)
        const float* __restrict__ bh1, const float* __restrict__ bz1,
        float* __restrict__ out, int use_gf32) {

    __shared__ char ldsX[16 * 1040];
    __shared__ char ldsY[16 * 1040];
    __shared__ float accS[2][4][16][17];

    const int tid = threadIdx.x;
    const int l = tid & 63, wv = tid >> 6, q = l >> 4, c = l & 15;
    const int gate = wv >> 2, ti = wv & 3;           // 8 waves = 2 gates x 4 tiles
    const bool isA = (blockIdx.x < 8);
    const int wg = blockIdx.x & 7;
    const int fbase = wg * 64;

    const int eb  = tid >> 5;                        // batch
    const int fpl = tid & 31;
    const int f0  = 2 * fpl;
    const int gf  = fbase + f0;                      // global feature (even)
    const int eti = f0 >> 4, efi = f0 & 15;

    int dead = 0;                                    // tid0 only: poll fail-safe

    if (isA) {
        // ---- layer 0 ----
        const _Float16* U = (gate == 0) ? U0z : U0h;
        const int urow = fbase + ti * 16 + c;
        half8 u[16];
#pragma unroll
        for (int ks = 0; ks < 16; ++ks)
            u[ks] = *(const half8*)(U + (size_t)urow * HDIM + ks * 32 + q * 8);
#pragma unroll
        for (int ks = 0; ks < 16; ++ks)
            asm volatile("" : "+v"(u[ks]));

        float h0 = 0.f, h1 = 0.f;
        float gw0[2], gw1[2], gz0[2], gz1[2];        // 2-step gate prefetch
        auto gload = [&](int t, int s) {
            const int row = t * BATCH + eb;
            if (use_gf32) {
                float2 a2 = *(const float2*)(gates32 + (size_t)row * NGATES + gf);
                float2 b2 = *(const float2*)(gates32 + (size_t)row * NGATES + 512 + gf);
                gw0[s] = a2.x; gw1[s] = a2.y; gz0[s] = b2.x; gz1[s] = b2.y;
            } else {
                union { uint32_t u; _Float16 h[2]; } ua, ub;
                ua.u = *(const uint32_t*)(gates16 + (size_t)row * NGATES + gf);
                ub.u = *(const uint32_t*)(gates16 + (size_t)row * NGATES + 512 + gf);
                gw0[s] = (float)ua.h[0]; gw1[s] = (float)ua.h[1];
                gz0[s] = (float)ub.h[0]; gz1[s] = (float)ub.h[1];
            }
        };
        gload(0, 0);
        gload(1, 1);

        for (int t = 0; t < T_STEPS; ++t) {
            // gate: H1TX[t] complete == all layer-0 flags >= t
            if (tid == 0 && !dead) {
                int bud = POLL_BUDGET;
                const unsigned tt = (unsigned)t;
                for (;;) {
                    uintx4 fa, fb;
                    ld8f(flg, fa, fb);
                    unsigned ok = 1u;
#pragma unroll
                    for (int i = 0; i < 4; ++i) {
                        ok &= (fa[i] >= tt) ? 1u : 0u;
                        ok &= (fb[i] >= tt) ? 1u : 0u;
                    }
                    if (ok) break;
                    __builtin_amdgcn_s_sleep(1);
                    if (--bud < 0) { dead = 1; break; }
                }
            }
            __syncthreads();

            // consume slot s into locals BEFORE the t+2 prefetch overwrites it
            const int s = t & 1;
            const float cw0 = gw0[s], cw1 = gw1[s], cz0 = gz0[s], cz1 = gz1[s];

            uintx4 A, B;
            ld32B((const char*)H1TX + (size_t)t * SNAPB + tid * 32, A, B);
            // issue the t+2 gate prefetch NOW: it completes during the MFMA phase,
            // so the end-of-step drain waits only on the exchange store
            if (t + 2 < T_STEPS) gload(t + 2, s);
            scat(ldsX, tid, A, B);
            __syncthreads();

            floatx4 ac0 = {0.f,0.f,0.f,0.f}, ac1 = {0.f,0.f,0.f,0.f};
            floatx4 ac2 = {0.f,0.f,0.f,0.f}, ac3 = {0.f,0.f,0.f,0.f};
#pragma unroll
            for (int ks = 0; ks < 16; ks += 4) {
                half8 a0 = *(const half8*)(ldsX + (ks    ) * 1040 + l * 16);
                half8 a1 = *(const half8*)(ldsX + (ks + 1) * 1040 + l * 16);
                half8 a2 = *(const half8*)(ldsX + (ks + 2) * 1040 + l * 16);
                half8 a3 = *(const half8*)(ldsX + (ks + 3) * 1040 + l * 16);
                ac0 = __builtin_amdgcn_mfma_f32_16x16x32_f16(a0, u[ks    ], ac0, 0, 0, 0);
                ac1 = __builtin_amdgcn_mfma_f32_16x16x32_f16(a1, u[ks + 1], ac1, 0, 0, 0);
                ac2 = __builtin_amdgcn_mfma_f32_16x16x32_f16(a2, u[ks + 2], ac2, 0, 0, 0);
                ac3 = __builtin_amdgcn_mfma_f32_16x16x32_f16(a3, u[ks + 3], ac3, 0, 0, 0);
            }
            floatx4 acc = (ac0 + ac1) + (ac2 + ac3);
#pragma unroll
            for (int r = 0; r < 4; ++r) accS[gate][ti][c][q * 4 + r] = acc[r];
            __syncthreads();

            float Sz0 = accS[0][eti][efi][eb],     Sh0 = accS[1][eti][efi][eb];
            float Sz1 = accS[0][eti][efi + 1][eb], Sh1 = accS[1][eti][efi + 1][eb];

            float z0 = 1.f / (1.f + __expf(-(cz0 + Sz0)));
            float z1 = 1.f / (1.f + __expf(-(cz1 + Sz1)));
            float hc0 = fmaxf(0.f, cw0 + Sh0);
            float hc1 = fmaxf(0.f, cw1 + Sh1);
            h0 = z0 * h0 + (1.f - z0) * hc0;
            h1 = z1 * h1 + (1.f - z1) * hc1;

            union { _Float16 h[2]; uint32_t u; } pk;
            pk.h[0] = (_Float16)h0; pk.h[1] = (_Float16)h1;
            st32cc((uint32_t*)((char*)H1TX + (size_t)(t + 1) * SNAPB + (eb * HDIM + gf) * 2), pk.u);

            __builtin_amdgcn_s_waitcnt(0);           // data acked at MALL
            __syncthreads();
            if (tid == 0) st32cc(&flg[wg], (unsigned)(t + 1));   // release
        }
    } else {
        // ---- layer 1 (input projection folded in) ----
        const _Float16* Wm = (gate == 0) ? W1z : W1h;
        const _Float16* Um = (gate == 0) ? U1z : U1h;
        const int urow = fbase + ti * 16 + c;
        half8 w[16], u[16];
#pragma unroll
        for (int ks = 0; ks < 16; ++ks) {
            w[ks] = *(const half8*)(Wm + (size_t)urow * HDIM + ks * 32 + q * 8);
            u[ks] = *(const half8*)(Um + (size_t)urow * HDIM + ks * 32 + q * 8);
        }
#pragma unroll
        for (int ks = 0; ks < 16; ++ks) {
            asm volatile("" : "+v"(w[ks]));
            asm volatile("" : "+v"(u[ks]));
        }

        const float bzv0 = bz1[gf], bzv1 = bz1[gf + 1];
        const float bhv0 = bh1[gf], bhv1 = bh1[gf + 1];
        float h0 = 0.f, h1 = 0.f;

        for (int t = 0; t < T_STEPS; ++t) {
            // gate: H1TX[t+1] (flagsA >= t+1) and exC[t&1] (flagsC >= t)
            if (tid == 0 && !dead) {
                int bud = POLL_BUDGET;
                const unsigned ta = (unsigned)(t + 1), tc = (unsigned)t;
                for (;;) {
                    uintx4 fa, fb, fc, fd;
                    ld16f(flg, fa, fb, fc, fd);
                    unsigned ok = 1u;
#pragma unroll
                    for (int i = 0; i < 4; ++i) {
                        ok &= (fa[i] >= ta) ? 1u : 0u;
                        ok &= (fb[i] >= ta) ? 1u : 0u;
                        ok &= (fc[i] >= tc) ? 1u : 0u;
                        ok &= (fd[i] >= tc) ? 1u : 0u;
                    }
                    if (ok) break;
                    __builtin_amdgcn_s_sleep(1);
                    if (--bud < 0) { dead = 1; break; }
                }
            }
            __syncthreads();

            uintx4 A, B, C, D;
            ld32Bx2((const char*)H1TX + (size_t)(t + 1) * SNAPB + tid * 32,
                    (const char*)exC + (size_t)(t & 1) * SNAPB + tid * 32, A, B, C, D);
            scat(ldsX, tid, A, B);
            scat(ldsY, tid, C, D);
            __syncthreads();

            floatx4 ac0 = {0.f,0.f,0.f,0.f}, ac1 = {0.f,0.f,0.f,0.f};
            floatx4 ac2 = {0.f,0.f,0.f,0.f}, ac3 = {0.f,0.f,0.f,0.f};
#pragma unroll
            for (int ks = 0; ks < 16; ks += 4) {
                half8 a0 = *(const half8*)(ldsX + (ks    ) * 1040 + l * 16);
                half8 a1 = *(const half8*)(ldsX + (ks + 1) * 1040 + l * 16);
                half8 a2 = *(const half8*)(ldsX + (ks + 2) * 1040 + l * 16);
                half8 a3 = *(const half8*)(ldsX + (ks + 3) * 1040 + l * 16);
                ac0 = __builtin_amdgcn_mfma_f32_16x16x32_f16(a0, w[ks    ], ac0, 0, 0, 0);
                ac1 = __builtin_amdgcn_mfma_f32_16x16x32_f16(a1, w[ks + 1], ac1, 0, 0, 0);
                ac2 = __builtin_amdgcn_mfma_f32_16x16x32_f16(a2, w[ks + 2], ac2, 0, 0, 0);
                ac3 = __builtin_amdgcn_mfma_f32_16x16x32_f16(a3, w[ks + 3], ac3, 0, 0, 0);
            }
#pragma unroll
            for (int ks = 0; ks < 16; ks += 4) {
                half8 a0 = *(const half8*)(ldsY + (ks    ) * 1040 + l * 16);
                half8 a1 = *(const half8*)(ldsY + (ks + 1) * 1040 + l * 16);
                half8 a2 = *(const half8*)(ldsY + (ks + 2) * 1040 + l * 16);
                half8 a3 = *(const half8*)(ldsY + (ks + 3) * 1040 + l * 16);
                ac0 = __builtin_amdgcn_mfma_f32_16x16x32_f16(a0, u[ks    ], ac0, 0, 0, 0);
                ac1 = __builtin_amdgcn_mfma_f32_16x16x32_f16(a1, u[ks + 1], ac1, 0, 0, 0);
                ac2 = __builtin_amdgcn_mfma_f32_16x16x32_f16(a2, u[ks + 2], ac2, 0, 0, 0);
                ac3 = __builtin_amdgcn_mfma_f32_16x16x32_f16(a3, u[ks + 3], ac3, 0, 0, 0);
            }
            floatx4 acc = (ac0 + ac1) + (ac2 + ac3);
#pragma unroll
            for (int r = 0; r < 4; ++r) accS[gate][ti][c][q * 4 + r] = acc[r];
            __syncthreads();

            float Sz0 = accS[0][eti][efi][eb],     Sh0 = accS[1][eti][efi][eb];
            float Sz1 = accS[0][eti][efi + 1][eb], Sh1 = accS[1][eti][efi + 1][eb];

            float z0 = 1.f / (1.f + __expf(-(bzv0 + Sz0)));
            float z1 = 1.f / (1.f + __expf(-(bzv1 + Sz1)));
            float hc0 = fmaxf(0.f, bhv0 + Sh0);
            float hc1 = fmaxf(0.f, bhv1 + Sh1);
            h0 = z0 * h0 + (1.f - z0) * hc0;
            h1 = z1 * h1 + (1.f - z1) * hc1;

            union { _Float16 h[2]; uint32_t u; } pk;
            pk.h[0] = (_Float16)h0; pk.h[1] = (_Float16)h1;
            st32cc((uint32_t*)((char*)exC + (size_t)((t + 1) & 1) * SNAPB + (eb * HDIM + gf) * 2), pk.u);

            float2 o; o.x = h0; o.y = h1;
            *(float2*)(out + (size_t)(t * BATCH + eb) * HDIM + gf) = o;  // final output (plain)

            __builtin_amdgcn_s_waitcnt(0);
            __syncthreads();
            if (tid == 0) st32cc(&flg[8 + wg], (unsigned)(t + 1));
        }
    }
}

// ---------------- host ----------------

extern "C" void kernel_launch(void* const* d_in, const int* in_sizes, int n_in,
                              void* d_out, int out_size, void* d_ws, size_t ws_size,
                              hipStream_t stream) {
    const float* x   = (const float*)d_in[0];
    const float* Wh0 = (const float*)d_in[1];
    const float* bh0 = (const float*)d_in[2];
    const float* Wz0 = (const float*)d_in[3];
    const float* bz0 = (const float*)d_in[4];
    const float* Uh0 = (const float*)d_in[5];
    const float* Uz0 = (const float*)d_in[6];
    const float* Wh1 = (const float*)d_in[7];
    const float* bh1 = (const float*)d_in[8];
    const float* Wz1 = (const float*)d_in[9];
    const float* bz1 = (const float*)d_in[10];
    const float* Uh1 = (const float*)d_in[11];
    const float* Uz1 = (const float*)d_in[12];
    float* out = (float*)d_out;

    uint8_t* ws = (uint8_t*)d_ws;
    size_t off = 0;
    auto alloc = [&](size_t b) { size_t o = off; off += (b + 255) & ~(size_t)255; return o; };

    const size_t H1TB = (size_t)(T_STEPS + 1) * SNAPB;   // +1 = zeroed h(-1) slot
    size_t o_flg  = alloc(256);                          // flg[16]
    size_t o_exC  = alloc(2 * SNAPB);                    // contiguous with flg
    size_t o_h1t  = alloc(H1TB);                         // contiguous with exC; slot0 zeroed
    size_t o_U0z  = alloc((size_t)HDIM * HDIM * 2);
    size_t o_U0h  = alloc((size_t)HDIM * HDIM * 2);
    size_t o_U1z  = alloc((size_t)HDIM * HDIM * 2);
    size_t o_U1h  = alloc((size_t)HDIM * HDIM * 2);
    size_t o_W1z  = alloc((size_t)HDIM * HDIM * 2);
    size_t o_W1h  = alloc((size_t)HDIM * HDIM * 2);
    size_t o_Wc0  = alloc((size_t)NGATES * FPAD * 2);
    size_t o_b0   = alloc(1024 * 4);
    size_t o_xb   = alloc((size_t)MROWS * FPAD * 2);
    size_t o_g    = off;
    size_t need32 = off + (size_t)MROWS * NGATES * 4;
    int use_gf32 = (ws_size >= need32) ? 1 : 0;

    unsigned int* FLG = (unsigned int*)(ws + o_flg);
    _Float16* EXC  = (_Float16*)(ws + o_exC);
    _Float16* H1TX = (_Float16*)(ws + o_h1t);
    _Float16* U0Z = (_Float16*)(ws + o_U0z);
    _Float16* U0H = (_Float16*)(ws + o_U0h);
    _Float16* U1Z = (_Float16*)(ws + o_U1z);
    _Float16* U1H = (_Float16*)(ws + o_U1h);
    _Float16* W1Z = (_Float16*)(ws + o_W1z);
    _Float16* W1H = (_Float16*)(ws + o_W1h);
    _Float16* WC0 = (_Float16*)(ws + o_Wc0);
    float*    B0  = (float*)(ws + o_b0);
    _Float16* XB  = (_Float16*)(ws + o_xb);
    float*    G32 = (float*)(ws + o_g);
    _Float16* G16 = (_Float16*)(ws + o_g);

    // zero flags + exC ring + the h(-1) snapshot (contiguous, 256-aligned sizes)
    hipMemsetAsync(ws + o_flg, 0, 256 + 2 * SNAPB + SNAPB, stream);

    // fp32 -> fp16 conversions (with K padding for layer-0 GEMM)
    cvt_pad<<<MROWS, 256, 0, stream>>>(x, XB, FDIM, FPAD);
    cvt_pad<<<512, 256, 0, stream>>>(Wh0, WC0,              FDIM, FPAD);
    cvt_pad<<<512, 256, 0, stream>>>(Wz0, WC0 + 512 * FPAD, FDIM, FPAD);
    cvt_pad<<<512, 256, 0, stream>>>(Uz0, U0Z, HDIM, HDIM);
    cvt_pad<<<512, 256, 0, stream>>>(Uh0, U0H, HDIM, HDIM);
    cvt_pad<<<512, 256, 0, stream>>>(Uz1, U1Z, HDIM, HDIM);
    cvt_pad<<<512, 256, 0, stream>>>(Uh1, U1H, HDIM, HDIM);
    cvt_pad<<<512, 256, 0, stream>>>(Wz1, W1Z, HDIM, HDIM);
    cvt_pad<<<512, 256, 0, stream>>>(Wh1, W1H, HDIM, HDIM);
    cat2<<<4, 256, 0, stream>>>(bh0, bz0, B0);

    // layer-0 gates GEMM (layer-1 projection folded into the scan)
    dim3 gg(NGATES / 128, (MROWS + 127) / 128);
    gemm_tn<<<gg, 256, 0, stream>>>(XB, WC0, B0, G32, G16, MROWS, FPAD, use_gf32);

    // fused 2-layer scan: exactly 16 WGs, flag-gated MALL exchange
    ligru_fused<<<16, 512, 0, stream>>>(G32, G16, U0Z, U0H, U1Z, U1H, W1Z, W1H,
                                        FLG, EXC, H1TX, bh1, bz1, out, use_gf32);

    (void)in_sizes; (void)n_in; (void)out_size;
}

// Round 9
// 3697.549 us; speedup vs baseline: 1.5037x; 1.3457x over previous
//
#include <hip/hip_runtime.h>
#include <cstdint>
#include <cstddef>

typedef _Float16 half8  __attribute__((ext_vector_type(8)));
typedef float    floatx4 __attribute__((ext_vector_type(4)));
typedef unsigned int uintx4 __attribute__((ext_vector_type(4)));

#define T_STEPS 1500
#define BATCH   16
#define FDIM    440
#define FPAD    448
#define HDIM    512
#define MROWS   (T_STEPS*BATCH)   /* 24000 */
#define NGATES  1024
#define SNAPE   8192              /* f16 elems per state snapshot (16x512) */
#define SNAPB   (SNAPE*2)         /* 16 KB */
#define POLL_BUDGET (1 << 14)
#define SENT 0xFFFFFFFFu          /* two f16 NaN(0xFFFF) halves; never produced by (f16)finite */

// ---------------- small utility kernels ----------------

__global__ __launch_bounds__(256) void cvt_pad(const float* __restrict__ src,
                                               _Float16* __restrict__ dst,
                                               int src_cols, int dst_cols) {
    int row = blockIdx.x;
    for (int k = threadIdx.x; k < dst_cols; k += 256) {
        float v = (k < src_cols) ? src[(size_t)row * src_cols + k] : 0.f;
        dst[(size_t)row * dst_cols + k] = (_Float16)v;
    }
}

__global__ __launch_bounds__(256) void cat2(const float* __restrict__ a,
                                            const float* __restrict__ b,
                                            float* __restrict__ dst) {
    int i = blockIdx.x * 256 + threadIdx.x;
    if (i < 1024) dst[i] = (i < 512) ? a[i] : b[i - 512];
}

// ---------------- GEMM: C[M,1024] = A[M,Kp] * B[1024,Kp]^T + bias (layer 0 gates) ----

__global__ __launch_bounds__(256) void gemm_tn(const _Float16* __restrict__ A,
                                               const _Float16* __restrict__ B,
                                               const float* __restrict__ bias,
                                               float* __restrict__ C32,
                                               _Float16* __restrict__ C16,
                                               int M, int Kp, int use_f32) {
    __shared__ _Float16 As[128 * 40];
    __shared__ _Float16 Bs[128 * 40];

    const int tid = threadIdx.x;
    const int wv = tid >> 6, l = tid & 63, q = l >> 4, c = l & 15;
    const int wr = wv >> 1, wc = wv & 1;
    const int m0 = blockIdx.y * 128, n0 = blockIdx.x * 128;

    floatx4 acc[4][4] = {};

    for (int kt = 0; kt < Kp; kt += 32) {
#pragma unroll
        for (int i = 0; i < 2; ++i) {
            int s = tid + i * 256;
            int row = s >> 2, qq = s & 3;
            uint4 va = {0u, 0u, 0u, 0u};
            int gm = m0 + row;
            if (gm < M) va = *(const uint4*)(A + (size_t)gm * Kp + kt + qq * 8);
            *(uint4*)(As + row * 40 + qq * 8) = va;
            uint4 vb = *(const uint4*)(B + (size_t)(n0 + row) * Kp + kt + qq * 8);
            *(uint4*)(Bs + row * 40 + qq * 8) = vb;
        }
        __syncthreads();

        half8 af[4], bf[4];
#pragma unroll
        for (int mi = 0; mi < 4; ++mi)
            af[mi] = *(const half8*)(As + (wr * 64 + mi * 16 + c) * 40 + q * 8);
#pragma unroll
        for (int ni = 0; ni < 4; ++ni)
            bf[ni] = *(const half8*)(Bs + (wc * 64 + ni * 16 + c) * 40 + q * 8);
#pragma unroll
        for (int mi = 0; mi < 4; ++mi)
#pragma unroll
            for (int ni = 0; ni < 4; ++ni)
                acc[mi][ni] = __builtin_amdgcn_mfma_f32_16x16x32_f16(af[mi], bf[ni], acc[mi][ni], 0, 0, 0);
        __syncthreads();
    }

#pragma unroll
    for (int ni = 0; ni < 4; ++ni) {
        int n = n0 + wc * 64 + ni * 16 + c;
        float bv = bias[n];
#pragma unroll
        for (int mi = 0; mi < 4; ++mi) {
#pragma unroll
            for (int r = 0; r < 4; ++r) {
                int gm = m0 + wr * 64 + mi * 16 + q * 4 + r;
                if (gm < M) {
                    float v = acc[mi][ni][r] + bv;
                    if (use_f32) C32[(size_t)gm * NGATES + n] = v;
                    else         C16[(size_t)gm * NGATES + n] = (_Float16)v;
                }
            }
        }
    }
}

// ---------------- MALL-coherent exchange primitives (sc0 sc1 = agent scope) ----------------

__device__ __forceinline__ void st32cc(uint32_t* p, uint32_t v) {
    asm volatile("global_store_dword %0, %1, off sc0 sc1" :: "v"(p), "v"(v) : "memory");
}
__device__ __forceinline__ void ld32B(const char* p, uintx4& A, uintx4& B) {
    asm volatile("global_load_dwordx4 %0, %2, off sc0 sc1\n\t"
                 "global_load_dwordx4 %1, %2, off offset:16 sc0 sc1\n\t"
                 "s_waitcnt vmcnt(0)"
                 : "=&v"(A), "=&v"(B) : "v"(p) : "memory");
}
__device__ __forceinline__ void ld32Bx2(const char* p1, const char* p2,
                                        uintx4& A, uintx4& B, uintx4& C, uintx4& D) {
    asm volatile("global_load_dwordx4 %0, %4, off sc0 sc1\n\t"
                 "global_load_dwordx4 %1, %4, off offset:16 sc0 sc1\n\t"
                 "global_load_dwordx4 %2, %5, off sc0 sc1\n\t"
                 "global_load_dwordx4 %3, %5, off offset:16 sc0 sc1\n\t"
                 "s_waitcnt vmcnt(0)"
                 : "=&v"(A), "=&v"(B), "=&v"(C), "=&v"(D) : "v"(p1), "v"(p2) : "memory");
}
// scatter thread j's 32B (feats [(j&31)*16, +16) of batch j>>5) into frag-major LDS
__device__ __forceinline__ void scat(char* lds, int j, uintx4 A, uintx4 B) {
    const int b = j >> 5, g = j & 31;
    const int ks = g >> 1, qp = (g & 1) * 2;
    *(uintx4*)(lds + ks * 1040 + (qp * 16 + b) * 16)       = A;
    *(uintx4*)(lds + ks * 1040 + ((qp + 1) * 16 + b) * 16) = B;
}

__device__ __forceinline__ unsigned valid8(const uintx4& A, const uintx4& B) {
    unsigned ok = 1u;
#pragma unroll
    for (int i = 0; i < 4; ++i) {
        ok &= (A[i] != SENT) ? 1u : 0u;
        ok &= (B[i] != SENT) ? 1u : 0u;
    }
    return ok;
}

// ---------------- fused 2-layer persistent scan, SENTINEL-POLLED exchange ----------------
// 16 WGs x 512 thr. WGs 0-7: layer-0 (64 feats each); WGs 8-15: layer-1.
//
// R9 protocol change: NO FLAGS. Both h histories (H1TX for layer-0, H2TX for
// layer-1) are append-only [T_STEPS+1][SNAPE], pre-filled with 0xFF sentinel
// (f16 NaN pattern: a stored dword from (f16)finite casts can never equal
// 0xFFFFFFFF). Each consumer thread polls ITS OWN 32B until no dword is
// sentinel -- the successful poll IS the data read. This merges the old
// poll-detect RT and data-read RT, and removes the producer-side
// s_waitcnt(0)+flag publish entirely (stores are fire-and-forget; the ack
// overlaps the consumer poll). Slot 0 of each history = zeroed h(-1).
// Failure mode: per-thread poll budget exhausts -> garbage -> loud absmax fail.
// accS padded [16]->[17] (R5). 4-chain MFMA (R8).

__global__ __launch_bounds__(512, 1) void ligru_fused(
        const float* __restrict__ gates32, const _Float16* __restrict__ gates16,
        const _Float16* __restrict__ U0z, const _Float16* __restrict__ U0h,
        const _Float16* __restrict__ U1z, const _Float16* __restrict__ U1h,
        const _Float16* __restrict__ W1z, const _Float16* __restrict__ W1h,
        _Float16* __restrict__ H1TX,        // [T_STEPS+1][SNAPE]; slot 0 = zeroed h(-1)
        _Float16* __restrict__ H2TX,        // [T_STEPS+1][SNAPE]; slot 0 = zeroed h(-1)
        const float* __restrict__ bh1, const float* __restrict__ bz1,
        float* __restrict__ out, int use_gf32) {

    __shared__ char ldsX[16 * 1040];
    __shared__ char ldsY[16 * 1040];
    __shared__ float accS[2][4][16][17];

    const int tid = threadIdx.x;
    const int l = tid & 63, wv = tid >> 6, q = l >> 4, c = l & 15;
    const int gate = wv >> 2, ti = wv & 3;           // 8 waves = 2 gates x 4 tiles
    const bool isA = (blockIdx.x < 8);
    const int wg = blockIdx.x & 7;
    const int fbase = wg * 64;

    const int eb  = tid >> 5;                        // batch
    const int fpl = tid & 31;
    const int f0  = 2 * fpl;
    const int gf  = fbase + f0;                      // global feature (even)
    const int eti = f0 >> 4, efi = f0 & 15;

    if (isA) {
        // ---- layer 0 ----
        const _Float16* U = (gate == 0) ? U0z : U0h;
        const int urow = fbase + ti * 16 + c;
        half8 u[16];
#pragma unroll
        for (int ks = 0; ks < 16; ++ks)
            u[ks] = *(const half8*)(U + (size_t)urow * HDIM + ks * 32 + q * 8);
#pragma unroll
        for (int ks = 0; ks < 16; ++ks)
            asm volatile("" : "+v"(u[ks]));

        float h0 = 0.f, h1 = 0.f;
        float gw0[2], gw1[2], gz0[2], gz1[2];        // 2-step gate prefetch
        auto gload = [&](int t, int s) {
            const int row = t * BATCH + eb;
            if (use_gf32) {
                float2 a2 = *(const float2*)(gates32 + (size_t)row * NGATES + gf);
                float2 b2 = *(const float2*)(gates32 + (size_t)row * NGATES + 512 + gf);
                gw0[s] = a2.x; gw1[s] = a2.y; gz0[s] = b2.x; gz1[s] = b2.y;
            } else {
                union { uint32_t u; _Float16 h[2]; } ua, ub;
                ua.u = *(const uint32_t*)(gates16 + (size_t)row * NGATES + gf);
                ub.u = *(const uint32_t*)(gates16 + (size_t)row * NGATES + 512 + gf);
                gw0[s] = (float)ua.h[0]; gw1[s] = (float)ua.h[1];
                gz0[s] = (float)ub.h[0]; gz1[s] = (float)ub.h[1];
            }
        };
        gload(0, 0);
        gload(1, 1);

        for (int t = 0; t < T_STEPS; ++t) {
            // per-thread sentinel poll on H1TX[t] (own 32B) -- poll IS the read
            const char* src = (const char*)H1TX + (size_t)t * SNAPB + tid * 32;
            uintx4 A, B;
            {
                int bud = POLL_BUDGET;
                for (;;) {
                    ld32B(src, A, B);
                    if (valid8(A, B)) break;
                    if (--bud < 0) break;            // loud failure via absmax
                }
            }

            // consume gate slot s into locals BEFORE the t+2 prefetch overwrites it
            const int s = t & 1;
            const float cw0 = gw0[s], cw1 = gw1[s], cz0 = gz0[s], cz1 = gz1[s];
            if (t + 2 < T_STEPS) gload(t + 2, s);

            scat(ldsX, tid, A, B);
            __syncthreads();                          // B1: scat done, ldsX ready

            floatx4 ac0 = {0.f,0.f,0.f,0.f}, ac1 = {0.f,0.f,0.f,0.f};
            floatx4 ac2 = {0.f,0.f,0.f,0.f}, ac3 = {0.f,0.f,0.f,0.f};
#pragma unroll
            for (int ks = 0; ks < 16; ks += 4) {
                half8 a0 = *(const half8*)(ldsX + (ks    ) * 1040 + l * 16);
                half8 a1 = *(const half8*)(ldsX + (ks + 1) * 1040 + l * 16);
                half8 a2 = *(const half8*)(ldsX + (ks + 2) * 1040 + l * 16);
                half8 a3 = *(const half8*)(ldsX + (ks + 3) * 1040 + l * 16);
                ac0 = __builtin_amdgcn_mfma_f32_16x16x32_f16(a0, u[ks    ], ac0, 0, 0, 0);
                ac1 = __builtin_amdgcn_mfma_f32_16x16x32_f16(a1, u[ks + 1], ac1, 0, 0, 0);
                ac2 = __builtin_amdgcn_mfma_f32_16x16x32_f16(a2, u[ks + 2], ac2, 0, 0, 0);
                ac3 = __builtin_amdgcn_mfma_f32_16x16x32_f16(a3, u[ks + 3], ac3, 0, 0, 0);
            }
            floatx4 acc = (ac0 + ac1) + (ac2 + ac3);
#pragma unroll
            for (int r = 0; r < 4; ++r) accS[gate][ti][c][q * 4 + r] = acc[r];
            __syncthreads();                          // B2: accS ready; ldsX reads done

            float Sz0 = accS[0][eti][efi][eb],     Sh0 = accS[1][eti][efi][eb];
            float Sz1 = accS[0][eti][efi + 1][eb], Sh1 = accS[1][eti][efi + 1][eb];

            float z0 = 1.f / (1.f + __expf(-(cz0 + Sz0)));
            float z1 = 1.f / (1.f + __expf(-(cz1 + Sz1)));
            float hc0 = fmaxf(0.f, cw0 + Sh0);
            float hc1 = fmaxf(0.f, cw1 + Sh1);
            h0 = z0 * h0 + (1.f - z0) * hc0;
            h1 = z1 * h1 + (1.f - z1) * hc1;

            union { _Float16 h[2]; uint32_t u; } pk;
            pk.h[0] = (_Float16)h0; pk.h[1] = (_Float16)h1;
            // fire-and-forget: ack overlaps consumers' polls; no drain, no flag
            st32cc((uint32_t*)((char*)H1TX + (size_t)(t + 1) * SNAPB + (eb * HDIM + gf) * 2), pk.u);
        }
    } else {
        // ---- layer 1 (input projection folded in) ----
        const _Float16* Wm = (gate == 0) ? W1z : W1h;
        const _Float16* Um = (gate == 0) ? U1z : U1h;
        const int urow = fbase + ti * 16 + c;
        half8 w[16], u[16];
#pragma unroll
        for (int ks = 0; ks < 16; ++ks) {
            w[ks] = *(const half8*)(Wm + (size_t)urow * HDIM + ks * 32 + q * 8);
            u[ks] = *(const half8*)(Um + (size_t)urow * HDIM + ks * 32 + q * 8);
        }
#pragma unroll
        for (int ks = 0; ks < 16; ++ks) {
            asm volatile("" : "+v"(w[ks]));
            asm volatile("" : "+v"(u[ks]));
        }

        const float bzv0 = bz1[gf], bzv1 = bz1[gf + 1];
        const float bhv0 = bh1[gf], bhv1 = bh1[gf + 1];
        float h0 = 0.f, h1 = 0.f;

        for (int t = 0; t < T_STEPS; ++t) {
            // per-thread sentinel poll on H1TX[t+1] (l0 out at t) + H2TX[t] (own prev)
            const char* s1 = (const char*)H1TX + (size_t)(t + 1) * SNAPB + tid * 32;
            const char* s2 = (const char*)H2TX + (size_t)t * SNAPB + tid * 32;
            uintx4 A, B, C, D;
            {
                int bud = POLL_BUDGET;
                for (;;) {
                    ld32Bx2(s1, s2, A, B, C, D);
                    if (valid8(A, B) & valid8(C, D)) break;
                    if (--bud < 0) break;
                }
            }

            scat(ldsX, tid, A, B);
            scat(ldsY, tid, C, D);
            __syncthreads();                          // B1

            floatx4 ac0 = {0.f,0.f,0.f,0.f}, ac1 = {0.f,0.f,0.f,0.f};
            floatx4 ac2 = {0.f,0.f,0.f,0.f}, ac3 = {0.f,0.f,0.f,0.f};
#pragma unroll
            for (int ks = 0; ks < 16; ks += 4) {
                half8 a0 = *(const half8*)(ldsX + (ks    ) * 1040 + l * 16);
                half8 a1 = *(const half8*)(ldsX + (ks + 1) * 1040 + l * 16);
                half8 a2 = *(const half8*)(ldsX + (ks + 2) * 1040 + l * 16);
                half8 a3 = *(const half8*)(ldsX + (ks + 3) * 1040 + l * 16);
                ac0 = __builtin_amdgcn_mfma_f32_16x16x32_f16(a0, w[ks    ], ac0, 0, 0, 0);
                ac1 = __builtin_amdgcn_mfma_f32_16x16x32_f16(a1, w[ks + 1], ac1, 0, 0, 0);
                ac2 = __builtin_amdgcn_mfma_f32_16x16x32_f16(a2, w[ks + 2], ac2, 0, 0, 0);
                ac3 = __builtin_amdgcn_mfma_f32_16x16x32_f16(a3, w[ks + 3], ac3, 0, 0, 0);
            }
#pragma unroll
            for (int ks = 0; ks < 16; ks += 4) {
                half8 a0 = *(const half8*)(ldsY + (ks    ) * 1040 + l * 16);
                half8 a1 = *(const half8*)(ldsY + (ks + 1) * 1040 + l * 16);
                half8 a2 = *(const half8*)(ldsY + (ks + 2) * 1040 + l * 16);
                half8 a3 = *(const half8*)(ldsY + (ks + 3) * 1040 + l * 16);
                ac0 = __builtin_amdgcn_mfma_f32_16x16x32_f16(a0, u[ks    ], ac0, 0, 0, 0);
                ac1 = __builtin_amdgcn_mfma_f32_16x16x32_f16(a1, u[ks + 1], ac1, 0, 0, 0);
                ac2 = __builtin_amdgcn_mfma_f32_16x16x32_f16(a2, u[ks + 2], ac2, 0, 0, 0);
                ac3 = __builtin_amdgcn_mfma_f32_16x16x32_f16(a3, u[ks + 3], ac3, 0, 0, 0);
            }
            floatx4 acc = (ac0 + ac1) + (ac2 + ac3);
#pragma unroll
            for (int r = 0; r < 4; ++r) accS[gate][ti][c][q * 4 + r] = acc[r];
            __syncthreads();                          // B2

            float Sz0 = accS[0][eti][efi][eb],     Sh0 = accS[1][eti][efi][eb];
            float Sz1 = accS[0][eti][efi + 1][eb], Sh1 = accS[1][eti][efi + 1][eb];

            float z0 = 1.f / (1.f + __expf(-(bzv0 + Sz0)));
            float z1 = 1.f / (1.f + __expf(-(bzv1 + Sz1)));
            float hc0 = fmaxf(0.f, bhv0 + Sh0);
            float hc1 = fmaxf(0.f, bhv1 + Sh1);
            h0 = z0 * h0 + (1.f - z0) * hc0;
            h1 = z1 * h1 + (1.f - z1) * hc1;

            union { _Float16 h[2]; uint32_t u; } pk;
            pk.h[0] = (_Float16)h0; pk.h[1] = (_Float16)h1;
            st32cc((uint32_t*)((char*)H2TX + (size_t)(t + 1) * SNAPB + (eb * HDIM + gf) * 2), pk.u);

            float2 o; o.x = h0; o.y = h1;
            *(float2*)(out + (size_t)(t * BATCH + eb) * HDIM + gf) = o;  // final output (plain)
        }
    }
}

// ---------------- host ----------------

extern "C" void kernel_launch(void* const* d_in, const int* in_sizes, int n_in,
                              void* d_out, int out_size, void* d_ws, size_t ws_size,
                              hipStream_t stream) {
    const float* x   = (const float*)d_in[0];
    const float* Wh0 = (const float*)d_in[1];
    const float* bh0 = (const float*)d_in[2];
    const float* Wz0 = (const float*)d_in[3];
    const float* bz0 = (const float*)d_in[4];
    const float* Uh0 = (const float*)d_in[5];
    const float* Uz0 = (const float*)d_in[6];
    const float* Wh1 = (const float*)d_in[7];
    const float* bh1 = (const float*)d_in[8];
    const float* Wz1 = (const float*)d_in[9];
    const float* bz1 = (const float*)d_in[10];
    const float* Uh1 = (const float*)d_in[11];
    const float* Uz1 = (const float*)d_in[12];
    float* out = (float*)d_out;

    uint8_t* ws = (uint8_t*)d_ws;
    size_t off = 0;
    auto alloc = [&](size_t b) { size_t o = off; off += (b + 255) & ~(size_t)255; return o; };

    const size_t HTB = (size_t)(T_STEPS + 1) * SNAPB;    // 24.6 MB per history (+1 = h(-1))
    size_t o_h1t  = alloc(HTB);                          // sentinel-filled; slot0 zeroed
    size_t o_h2t  = alloc(HTB);                          // contiguous with o_h1t
    size_t o_U0z  = alloc((size_t)HDIM * HDIM * 2);
    size_t o_U0h  = alloc((size_t)HDIM * HDIM * 2);
    size_t o_U1z  = alloc((size_t)HDIM * HDIM * 2);
    size_t o_U1h  = alloc((size_t)HDIM * HDIM * 2);
    size_t o_W1z  = alloc((size_t)HDIM * HDIM * 2);
    size_t o_W1h  = alloc((size_t)HDIM * HDIM * 2);
    size_t o_Wc0  = alloc((size_t)NGATES * FPAD * 2);
    size_t o_b0   = alloc(1024 * 4);
    size_t o_xb   = alloc((size_t)MROWS * FPAD * 2);
    size_t o_g    = off;
    size_t need32 = off + (size_t)MROWS * NGATES * 4;
    int use_gf32 = (ws_size >= need32) ? 1 : 0;

    _Float16* H1TX = (_Float16*)(ws + o_h1t);
    _Float16* H2TX = (_Float16*)(ws + o_h2t);
    _Float16* U0Z = (_Float16*)(ws + o_U0z);
    _Float16* U0H = (_Float16*)(ws + o_U0h);
    _Float16* U1Z = (_Float16*)(ws + o_U1z);
    _Float16* U1H = (_Float16*)(ws + o_U1h);
    _Float16* W1Z = (_Float16*)(ws + o_W1z);
    _Float16* W1H = (_Float16*)(ws + o_W1h);
    _Float16* WC0 = (_Float16*)(ws + o_Wc0);
    float*    B0  = (float*)(ws + o_b0);
    _Float16* XB  = (_Float16*)(ws + o_xb);
    float*    G32 = (float*)(ws + o_g);
    _Float16* G16 = (_Float16*)(ws + o_g);

    // sentinel-fill both histories (contiguous: HTB is 256-aligned), then zero
    // slot 0 of each (= h(-1))
    hipMemsetAsync(ws + o_h1t, 0xFF, 2 * HTB, stream);
    hipMemsetAsync(ws + o_h1t, 0, SNAPB, stream);
    hipMemsetAsync(ws + o_h2t, 0, SNAPB, stream);

    // fp32 -> fp16 conversions (with K padding for layer-0 GEMM)
    cvt_pad<<<MROWS, 256, 0, stream>>>(x, XB, FDIM, FPAD);
    cvt_pad<<<512, 256, 0, stream>>>(Wh0, WC0,              FDIM, FPAD);
    cvt_pad<<<512, 256, 0, stream>>>(Wz0, WC0 + 512 * FPAD, FDIM, FPAD);
    cvt_pad<<<512, 256, 0, stream>>>(Uz0, U0Z, HDIM, HDIM);
    cvt_pad<<<512, 256, 0, stream>>>(Uh0, U0H, HDIM, HDIM);
    cvt_pad<<<512, 256, 0, stream>>>(Uz1, U1Z, HDIM, HDIM);
    cvt_pad<<<512, 256, 0, stream>>>(Uh1, U1H, HDIM, HDIM);
    cvt_pad<<<512, 256, 0, stream>>>(Wz1, W1Z, HDIM, HDIM);
    cvt_pad<<<512, 256, 0, stream>>>(Wh1, W1H, HDIM, HDIM);
    cat2<<<4, 256, 0, stream>>>(bh0, bz0, B0);

    // layer-0 gates GEMM (layer-1 projection folded into the scan)
    dim3 gg(NGATES / 128, (MROWS + 127) / 128);
    gemm_tn<<<gg, 256, 0, stream>>>(XB, WC0, B0, G32, G16, MROWS, FPAD, use_gf32);

    // fused 2-layer scan: exactly 16 WGs, sentinel-polled MALL exchange
    ligru_fused<<<16, 512, 0, stream>>>(G32, G16, U0Z, U0H, U1Z, U1H, W1Z, W1H,
                                        H1TX, H2TX, bh1, bz1, out, use_gf32);

    (void)in_sizes; (void)n_in; (void)out_size;
}